// Round 2
// baseline (244.514 us; speedup 1.0000x reference)
//
#include <hip/hip_runtime.h>
#include <math.h>

// DigitCaps dynamic routing, MFMA version, round 2.
// u[b,n,cl] = sum_j x[b,n,j] W[n,j,cl] per-n on v_mfma_f32_16x16x16f16
//   (M=16: one capsule c's 16 l, N=16: batch, K=16 with j=8 real).
// R2 changes vs R1 (which inferred ~31us/pass, latency-bound):
//  - No exec-masked loads: ALL lanes load (hi lanes mirror lo addresses, L1
//    broadcast); k=8..15 zeroed by masking only the B fragment (xf) -> the A
//    fragment may hold garbage. Removes the per-nn s_and_saveexec that
//    blocked software pipelining.
//  - Explicit next-nn prefetch issued before the MFMA+softmax of current nn;
//    #pragma unroll 2 renames the double-buffer copies away. Workspace is
//    padded so the always-taken prefetch stays in bounds.
//  - log2e folded into v at load time -> exp2f (saves 10 v_mul per nn).
// Routing stays in registers on the MFMA D layout: lane = (b=lane&15,
// l=4*(lane>>4)+reg); t[b,c] = 4 fma + shfl_xor(16) + shfl_xor(32).

namespace {
constexpr int B_   = 128;
constexpr int N_   = 4608;
constexpr int C_   = 10;
constexpr int L_   = 16;
constexpr int CL   = C_ * L_;            // 160
constexpr int NCHK = 256;                // partial chunks (grid.x)
constexpr int TILE_N = N_ / NCHK;        // 18 n per block
constexpr int BCL  = B_ * CL;            // 20480
constexpr int RED_G = 16;
constexpr int RED_K = NCHK / RED_G;      // 16
constexpr int WBLK = (N_ * CL) / 256;    // 2880 blocks: W pack
constexpr int XBLK = (B_ * N_) / 256;    // 2304 blocks: x convert
constexpr float LOG2E = 1.44269504088896340736f;
}

typedef _Float16 v4h __attribute__((ext_vector_type(4)));
typedef _Float16 v8h __attribute__((ext_vector_type(8)));
typedef float    v4f __attribute__((ext_vector_type(4)));

// W [N][8][160] f32 -> Wt [N][160][8] f16 (transpose j<->cl, pack)
// x [B][N][8]  f32 -> xh [B][N][8]  f16 (straight convert)
__global__ __launch_bounds__(256)
void conv_pack(const float* __restrict__ W, const float* __restrict__ x,
               v8h* __restrict__ Wt, v8h* __restrict__ xh)
{
  if ((int)blockIdx.x < WBLK) {
    const int t  = blockIdx.x * 256 + threadIdx.x;     // (n, cl)
    const int n  = t / CL, cl = t % CL;
    const float* p = W + (size_t)n * (8 * CL) + cl;
    v8h o;
#pragma unroll
    for (int j = 0; j < 8; ++j) o[j] = (_Float16)p[j * CL];
    Wt[t] = o;
  } else {
    const int t = ((int)blockIdx.x - WBLK) * 256 + threadIdx.x; // 8-float chunk
    const float4 a = ((const float4*)x)[(size_t)t * 2 + 0];
    const float4 b = ((const float4*)x)[(size_t)t * 2 + 1];
    v8h o = { (_Float16)a.x, (_Float16)a.y, (_Float16)a.z, (_Float16)a.w,
              (_Float16)b.x, (_Float16)b.y, (_Float16)b.z, (_Float16)b.w };
    xh[t] = o;
  }
}

// MODE 0: uniform coupling (1/10 folded into reduce_b scale)
// MODE 1: logits t = u.v0      MODE 2: logits t = u.(v0+v1)
template<int MODE>
__global__ __launch_bounds__(256, 2)
void pass_kernel(const _Float16* __restrict__ xh,
                 const _Float16* __restrict__ Wt,
                 const float* __restrict__ va,
                 const float* __restrict__ vb,
                 float* __restrict__ partials)      // [NCHK][B][C][L]
{
  const int lane = threadIdx.x & 63;
  const int wid  = threadIdx.x >> 6;     // 4 waves = 4 batch tiles of 16
  const int bl   = lane & 15;            // batch (B frag col / D col); cl row (A)
  const int hi   = lane >> 4;            // 0..3: l-quarter in D rows
  const int kh   = hi & 1;               // k-half for fragment loads (hi lanes mirror)
  const int b    = blockIdx.y * 64 + wid * 16 + bl;
  const int n0   = blockIdx.x * TILE_N;
  const bool lo  = lane < 32;            // lanes whose K slots are real (j=0..7)

  v4f vv[C_];                            // v[b][c][4*hi..+3] * log2e
  if (MODE >= 1) {
#pragma unroll
    for (int c = 0; c < C_; ++c) {
      v4f t = *(const v4f*)(va + ((size_t)b * C_ + c) * L_ + hi * 4);
      if (MODE == 2)
        t += *(const v4f*)(vb + ((size_t)b * C_ + c) * L_ + hi * 4);
      vv[c] = t * LOG2E;
    }
  }

  const v4f zf = {0.f, 0.f, 0.f, 0.f};
  v4f sacc[C_];
#pragma unroll
  for (int c = 0; c < C_; ++c) sacc[c] = zf;

  const _Float16* xp = xh + ((size_t)b * N_ + n0) * 8 + kh * 4;
  const _Float16* wp = Wt + ((size_t)n0 * CL + bl) * 8 + kh * 4;

  // prologue: fragments for nn = 0 (all lanes; no exec masking)
  v4h xf = *(const v4h*)xp;
  v4h wf[C_];
#pragma unroll
  for (int c = 0; c < C_; ++c)
    wf[c] = *(const v4h*)(wp + c * (16 * 8));

#pragma unroll 2
  for (int nn = 0; nn < TILE_N; ++nn) {
    // prefetch nn+1 (always in-bounds: workspace padded past the last row)
    const _Float16* xq = xp + (nn + 1) * 8;
    const _Float16* wq = wp + (size_t)(nn + 1) * (CL * 8);
    v4h xf_n = *(const v4h*)xq;
    v4h wf_n[C_];
#pragma unroll
    for (int c = 0; c < C_; ++c)
      wf_n[c] = *(const v4h*)(wq + c * (16 * 8));

    // zero the k=8..15 contribution via the B fragment only
    v4h xm = xf;
    if (!lo) { v4h z = {}; xm = z; }

    if (MODE == 0) {
#pragma unroll
      for (int c = 0; c < C_; ++c)
        sacc[c] = __builtin_amdgcn_mfma_f32_16x16x16f16(wf[c], xm, sacc[c], 0, 0, 0);
    } else {
      v4f u[C_];
#pragma unroll
      for (int c = 0; c < C_; ++c)
        u[c] = __builtin_amdgcn_mfma_f32_16x16x16f16(wf[c], xm, zf, 0, 0, 0);

      float tt[C_];
#pragma unroll
      for (int c = 0; c < C_; ++c) {
        float t = u[c][0] * vv[c][0];
        t = fmaf(u[c][1], vv[c][1], t);
        t = fmaf(u[c][2], vv[c][2], t);
        t = fmaf(u[c][3], vv[c][3], t);
        tt[c] = t;
      }
#pragma unroll
      for (int c = 0; c < C_; ++c) {
        tt[c] += __shfl_xor(tt[c], 16);
        tt[c] += __shfl_xor(tt[c], 32);
      }
      float es = 0.f;
#pragma unroll
      for (int c = 0; c < C_; ++c) { tt[c] = exp2f(tt[c]); es += tt[c]; }
      const float rs = __builtin_amdgcn_rcpf(es);
#pragma unroll
      for (int c = 0; c < C_; ++c) {
        const float w = tt[c] * rs;
#pragma unroll
        for (int i = 0; i < 4; ++i)
          sacc[c][i] = fmaf(w, u[c][i], sacc[c][i]);
      }
    }

    xf = xf_n;
#pragma unroll
    for (int c = 0; c < C_; ++c) wf[c] = wf_n[c];
  }

  float* pout = partials + ((size_t)blockIdx.x * B_ + b) * CL + hi * 4;
#pragma unroll
  for (int c = 0; c < C_; ++c)
    *(v4f*)(pout + c * L_) = sacc[c];
}

// Stage A: sum 256 chunks down to 16 groups (fully coalesced streaming)
__global__ __launch_bounds__(256)
void reduce_a(const float* __restrict__ p, float* __restrict__ p2) {
  const int t   = blockIdx.x * 256 + threadIdx.x;   // 0 .. 16*BCL-1
  const int idx = t % BCL;
  const int g   = t / BCL;
  float a = 0.f;
#pragma unroll
  for (int k = 0; k < RED_K; ++k)
    a += p[(size_t)(g * RED_K + k) * BCL + idx];
  p2[t] = a;
}

// Stage B: sum 16 groups, add bias, squash (16-lane shuffle for ||s||^2)
__global__ __launch_bounds__(256)
void reduce_b(const float* __restrict__ p2, const float* __restrict__ biases,
              float* __restrict__ vout, float scale) {
  const int idx = blockIdx.x * 256 + threadIdx.x;   // 0 .. BCL-1
  float a = 0.f;
#pragma unroll
  for (int g = 0; g < RED_G; ++g) a += p2[(size_t)g * BCL + idx];
  const float s = a * scale + biases[idx % CL];
  float n2 = s * s;
#pragma unroll
  for (int o = 8; o; o >>= 1) n2 += __shfl_xor(n2, o, 16);
  const float n = sqrtf(n2);
  const float f = n2 / ((1.f + n2) * (n + 1e-7f));
  vout[idx] = f * s;
}

extern "C" void kernel_launch(void* const* d_in, const int* in_sizes, int n_in,
                              void* d_out, int out_size, void* d_ws, size_t ws_size,
                              hipStream_t stream) {
  const float* x      = (const float*)d_in[0];
  const float* W      = (const float*)d_in[1];
  const float* biases = (const float*)d_in[2];
  float* out = (float*)d_out;

  // layout (with prefetch-overrun pads, 16B-aligned):
  _Float16* Wt  = (_Float16*)d_ws;                          // N*160*8 + pad
  _Float16* xhp = Wt + (size_t)N_ * CL * 8 + CL * 8;        // B*N*8 + pad
  float* partials = (float*)(xhp + (size_t)B_ * N_ * 8 + 64);
  float* p2 = partials + (size_t)NCHK * BCL;
  float* v0 = p2 + (size_t)RED_G * BCL;
  float* v1 = v0 + BCL;

  conv_pack<<<WBLK + XBLK, 256, 0, stream>>>(W, x, (v8h*)Wt, (v8h*)xhp);

  const dim3 pg(NCHK, 2), pb(256);

  pass_kernel<0><<<pg, pb, 0, stream>>>(xhp, Wt, nullptr, nullptr, partials);
  reduce_a<<<(RED_G * BCL) / 256, 256, 0, stream>>>(partials, p2);
  reduce_b<<<BCL / 256, 256, 0, stream>>>(p2, biases, v0, 0.1f);

  pass_kernel<1><<<pg, pb, 0, stream>>>(xhp, Wt, v0, nullptr, partials);
  reduce_a<<<(RED_G * BCL) / 256, 256, 0, stream>>>(partials, p2);
  reduce_b<<<BCL / 256, 256, 0, stream>>>(p2, biases, v1, 1.0f);

  pass_kernel<2><<<pg, pb, 0, stream>>>(xhp, Wt, v0, v1, partials);
  reduce_a<<<(RED_G * BCL) / 256, 256, 0, stream>>>(partials, p2);
  reduce_b<<<BCL / 256, 256, 0, stream>>>(p2, biases, out, 1.0f);
}